// Round 21
// baseline (112.079 us; speedup 1.0000x reference)
//
#include <hip/hip_runtime.h>
#include <math.h>

#define DIMC   256
#define NQ     4096
#define BATCH  4
#define NS     1024    // (H/SR)*(W/SR) = 32*32
#define WG     32
#define HG     32
#define NHEADS 8
#define HDIM   32
#define TILEK  128     // keys staged per LDS tile
#define KSTRIDE 40     // f16 per K row in LDS
#define VSTRIDE 136    // f16 per Vt row in LDS
#define WSTRIDE 264    // f16 per B row in LDS-staged GEMM
#define BUCKCAP 64     // tokens-per-cell bucket capacity (= wave size)
#define GCELLS 4       // cells per gather block
#define NSPLIT 2       // attn K-split
#define SCALE_ATTN 0.17677669529663687
#define LOG2E 1.4426950408889634
#define SCALE2F ((float)(SCALE_ATTN * LOG2E))

extern "C" __device__ float __ocml_native_exp2_f32(float);
#if __has_builtin(__builtin_amdgcn_exp2f)
#define EXP2(x) __builtin_amdgcn_exp2f(x)
#else
#define EXP2(x) __ocml_native_exp2_f32(x)
#endif

typedef _Float16 f16;
typedef __attribute__((ext_vector_type(8))) __bf16    bf16x8;
typedef __attribute__((ext_vector_type(8))) _Float16  f16x8;
typedef __attribute__((ext_vector_type(4))) _Float16  f16x4;
typedef __attribute__((ext_vector_type(4))) float     f32x4;

#define MFMA16B(A, B, C)  __builtin_amdgcn_mfma_f32_16x16x32_bf16((A), (B), (C), 0, 0, 0)
#define MFMA16F(A, B, C)  __builtin_amdgcn_mfma_f32_16x16x32_f16((A), (B), (C), 0, 0, 0)
#define MFMA16K16(A, B, C) __builtin_amdgcn_mfma_f32_16x16x16f16((A), (B), (C), 0, 0, 0)

static __device__ __forceinline__ unsigned short bf16_hi(float v) {
    return __builtin_bit_cast(unsigned short, (__bf16)v);
}

// ---------------- prep: wprep (y=0..4) + zero cursor (y=5) ----------------
__global__ __launch_bounds__(256) void prep_kernel(
    const float* __restrict__ Wsr, const float* __restrict__ Wq,
    const float* __restrict__ Wk, const float* __restrict__ Wv,
    const float* __restrict__ Wp,
    unsigned short* __restrict__ wsrh, unsigned short* __restrict__ wsrl,
    f16* __restrict__ wq16, f16* __restrict__ wkv, f16* __restrict__ wp16,
    int* __restrict__ cursor)
{
    int m = blockIdx.y;
    if (m == 5) {
        int i = blockIdx.x * 256 + threadIdx.x;
        if (i < BATCH * NS) cursor[i] = 0;
        return;
    }
    int i = (blockIdx.x * 256 + threadIdx.x) * 4;   // grid.x = 64 -> 65536 elems
    if (m == 0) {
        float4 v = *(const float4*)(Wsr + i);
        float vv[4] = {v.x, v.y, v.z, v.w};
        ushort4 h, l;
        unsigned short* hp = &h.x; unsigned short* lp = &l.x;
        #pragma unroll
        for (int j = 0; j < 4; j++) {
            __bf16 hb = (__bf16)vv[j];
            hp[j] = __builtin_bit_cast(unsigned short, hb);
            lp[j] = bf16_hi(vv[j] - (float)hb);
        }
        *(ushort4*)(wsrh + i) = h;
        *(ushort4*)(wsrl + i) = l;
    } else {
        const float* W = (m == 1) ? Wq : (m == 2) ? Wk : (m == 3) ? Wv : Wp;
        f16* O = (m == 1) ? wq16 : (m == 2) ? wkv
               : (m == 3) ? (wkv + DIMC * DIMC) : wp16;
        float4 v = *(const float4*)(W + i);
        f16x4 h = {(f16)v.x, (f16)v.y, (f16)v.z, (f16)v.w};
        *(f16x4*)(O + i) = h;
    }
}

// ---------------- build: token -> cell buckets (16K int atomics only) ----------------
__global__ __launch_bounds__(256) void build_kernel(
    const float* __restrict__ loc, int* __restrict__ cursor,
    int* __restrict__ bucket)
{
    int token = blockIdx.x * 256 + threadIdx.x;   // B*NQ
    int b = token >> 12;
    float lx = loc[token * 2 + 0];
    float ly = loc[token * 2 + 1];
    lx = fminf(fmaxf(lx, 0.f), 1.f) * (float)(WG - 1);
    ly = fminf(fmaxf(ly, 0.f), 1.f) * (float)(HG - 1);
    int ix = (int)rintf(lx);         // round-half-even, matches jnp.round
    int iy = (int)rintf(ly);
    int cell = b * NS + iy * WG + ix;
    int slot = atomicAdd(&cursor[cell], 1);
    if (slot < BUCKCAP) bucket[cell * BUCKCAP + slot] = token;
}

// ---------------- gather standalone (1024 blocks, 4 cells each) ----------------
__global__ __launch_bounds__(256) void gather_kernel(
    const float* __restrict__ xsrc, const float* __restrict__ csrc,
    const int* __restrict__ cursor, const int* __restrict__ bucket,
    float* __restrict__ feat, float* __restrict__ cnt, float* __restrict__ confsum)
{
    __shared__ int bks[GCELLS][BUCKCAP];
    __shared__ int ns[GCELLS];
    int cell0 = blockIdx.x * GCELLS;
    int tid = threadIdx.x;
    int jw = tid >> 6, slot = tid & 63;      // wave jw <-> cell jw
    int cj = cell0 + jw;
    int rawn = cursor[cj];
    if (slot == 0) ns[jw] = min(rawn, BUCKCAP);
    bks[jw][slot] = bucket[(size_t)cj * BUCKCAP + slot];
    __syncthreads();
    int nw = ns[jw];
    float cv = (slot < nw) ? csrc[bks[jw][slot]] : 0.f;
    #pragma unroll
    for (int off = 1; off < 64; off <<= 1) cv += __shfl_xor(cv, off);
    if (slot == 0) { confsum[cj] = cv; cnt[cj] = (float)rawn; }
    int c = tid;
    for (int j = 0; j < GCELLS; j++) {
        int n = ns[j];
        float s0 = 0.f, s1 = 0.f, s2 = 0.f, s3 = 0.f;
        int i = 0;
        for (; i + 4 <= n; i += 4) {
            s0 += xsrc[(size_t)bks[j][i]     * DIMC + c];
            s1 += xsrc[(size_t)bks[j][i + 1] * DIMC + c];
            s2 += xsrc[(size_t)bks[j][i + 2] * DIMC + c];
            s3 += xsrc[(size_t)bks[j][i + 3] * DIMC + c];
        }
        for (; i < n; i++)
            s0 += xsrc[(size_t)bks[j][i] * DIMC + c];
        feat[(size_t)(cell0 + j) * DIMC + c] = (s0 + s1) + (s2 + s3);
    }
}

// ---------------- bf16x2-split GEMM + fused featfin + LN stats + conf2: Wsr ----------------
__global__ __launch_bounds__(256) void gemm_sr_kernel(
    const float* __restrict__ A, const float* __restrict__ cnt,
    const float* __restrict__ confsum,
    const unsigned short* __restrict__ Whi, const unsigned short* __restrict__ Wlo,
    const float* __restrict__ bias, float* __restrict__ outF,
    float2* __restrict__ stats, float* __restrict__ conf2)
{
    int r0 = blockIdx.x * 16;               // 256 blocks
    int wave = threadIdx.x >> 6;
    int lane = threadIdx.x & 63;
    int s = lane & 15, g = lane >> 4;
    int arow = r0 + s;
    int cb = wave * 64;                     // wave's 64-col slice
    const float* ap = A + (size_t)arow * DIMC + 8 * g;
    float cv = cnt[arow];
    float invr = (cv > 0.f) ? 1.f / (cv + 1e-6f) : 0.f;

    f32x4 acc[4];
    #pragma unroll
    for (int cf = 0; cf < 4; cf++) {
        float bv = bias[cb + cf * 16 + s];
        acc[cf] = (f32x4){bv, bv, bv, bv};
    }

    #pragma unroll
    for (int kk = 0; kk < 8; kk++) {
        float4 a0 = *(const float4*)(ap + kk * 32);
        float4 a1 = *(const float4*)(ap + kk * 32 + 4);
        float av[8] = {a0.x, a0.y, a0.z, a0.w, a1.x, a1.y, a1.z, a1.w};
        bf16x8 ah, al;
        #pragma unroll
        for (int j = 0; j < 8; j++) {
            float v = av[j] * invr;              // fused featfin
            __bf16 hb = (__bf16)v;
            ah[j] = hb;
            al[j] = (__bf16)(v - (float)hb);
        }
        #pragma unroll
        for (int cf = 0; cf < 4; cf++) {
            size_t woff = (size_t)(cb + cf * 16 + s) * DIMC + kk * 32 + 8 * g;
            bf16x8 bh = *(const bf16x8*)(Whi + woff);
            bf16x8 bl = *(const bf16x8*)(Wlo + woff);
            acc[cf] = MFMA16B(ah, bh, acc[cf]);
            acc[cf] = MFMA16B(al, bh, acc[cf]);
            acc[cf] = MFMA16B(ah, bl, acc[cf]);
        }
    }

    int rbase = r0 + 4 * g;
    #pragma unroll
    for (int cf = 0; cf < 4; cf++) {
        int c = cb + cf * 16 + s;
        #pragma unroll
        for (int r = 0; r < 4; r++)
            outF[(size_t)(rbase + r) * DIMC + c] = acc[cf][r];
    }
    // fused LN stats
    float psum[4], psq[4];
    #pragma unroll
    for (int r = 0; r < 4; r++) {
        psum[r] = 0.f; psq[r] = 0.f;
        #pragma unroll
        for (int cf = 0; cf < 4; cf++) {
            float v = acc[cf][r];
            psum[r] += v; psq[r] += v * v;
        }
    }
    #pragma unroll
    for (int off = 1; off < 16; off <<= 1)
        #pragma unroll
        for (int r = 0; r < 4; r++) {
            psum[r] += __shfl_xor(psum[r], off);
            psq[r]  += __shfl_xor(psq[r], off);
        }
    __shared__ float ssum[4][16], ssq[4][16];
    if (s == 0)
        #pragma unroll
        for (int r = 0; r < 4; r++) {
            ssum[wave][4 * g + r] = psum[r];
            ssq[wave][4 * g + r]  = psq[r];
        }
    __syncthreads();
    if (threadIdx.x < 16) {
        int rr = threadIdx.x;
        float su = ssum[0][rr] + ssum[1][rr] + ssum[2][rr] + ssum[3][rr];
        float sq = ssq[0][rr] + ssq[1][rr] + ssq[2][rr] + ssq[3][rr];
        float mu  = su * (1.f / DIMC);
        float var = sq * (1.f / DIMC) - mu * mu;
        stats[r0 + rr] = make_float2(mu, rsqrtf(var + 1e-5f));
        float cv2 = cnt[r0 + rr];
        float iv2 = (cv2 > 0.f) ? 1.f / (cv2 + 1e-6f) : 0.f;
        conf2[r0 + rr] = confsum[r0 + rr] * iv2 * (float)LOG2E;
    }
}

// ---------------- fused LN + K/V GEMM (single f16 product) ----------------
__global__ __launch_bounds__(256) void gemm_kv_kernel(
    const float* __restrict__ xs, const float2* __restrict__ stats,
    const float* __restrict__ lng, const float* __restrict__ lnb,
    const f16* __restrict__ wkv, f16* __restrict__ k16, f16* __restrict__ vt16)
{
    int r0 = blockIdx.x * 16;
    int cb0 = blockIdx.y * 128;            // 0..384 over N=512
    int wave = threadIdx.x >> 6;
    int lane = threadIdx.x & 63;
    int s = lane & 15, g = lane >> 4;
    int arow = r0 + s;
    int cb = cb0 + wave * 32;
    float2 st = stats[arow];               // mu, rs
    const float* ap = xs + (size_t)arow * DIMC + 8 * g;

    f32x4 acc[2];
    acc[0] = (f32x4){0.f, 0.f, 0.f, 0.f};
    acc[1] = (f32x4){0.f, 0.f, 0.f, 0.f};

    #pragma unroll
    for (int kk = 0; kk < 8; kk++) {
        float4 a0 = *(const float4*)(ap + kk * 32);
        float4 a1 = *(const float4*)(ap + kk * 32 + 4);
        float4 g0 = *(const float4*)(lng + kk * 32 + 8 * g);
        float4 g1 = *(const float4*)(lng + kk * 32 + 8 * g + 4);
        float4 b0 = *(const float4*)(lnb + kk * 32 + 8 * g);
        float4 b1 = *(const float4*)(lnb + kk * 32 + 8 * g + 4);
        float av[8] = {a0.x, a0.y, a0.z, a0.w, a1.x, a1.y, a1.z, a1.w};
        float gv[8] = {g0.x, g0.y, g0.z, g0.w, g1.x, g1.y, g1.z, g1.w};
        float bv[8] = {b0.x, b0.y, b0.z, b0.w, b1.x, b1.y, b1.z, b1.w};
        f16x8 a;
        #pragma unroll
        for (int j = 0; j < 8; j++)
            a[j] = (f16)(((av[j] - st.x) * st.y) * gv[j] + bv[j]);
        #pragma unroll
        for (int cf = 0; cf < 2; cf++) {
            f16x8 bfrag = *(const f16x8*)(wkv + (size_t)(cb + cf * 16 + s) * DIMC
                                              + kk * 32 + 8 * g);
            acc[cf] = MFMA16F(a, bfrag, acc[cf]);
        }
    }

    int rbase = r0 + 4 * g;
    if (cb0 < 256) {                       // K channels: row-major
        #pragma unroll
        for (int cf = 0; cf < 2; cf++) {
            int c = cb + cf * 16 + s;
            #pragma unroll
            for (int r = 0; r < 4; r++)
                k16[(size_t)(rbase + r) * DIMC + c] = (f16)acc[cf][r];
        }
    } else {                               // V channels: transposed vt16
        int b = rbase >> 10;
        int key0 = rbase & 1023;
        #pragma unroll
        for (int cf = 0; cf < 2; cf++) {
            int cc = cb + cf * 16 + s - 256;
            f16x4 h;
            #pragma unroll
            for (int r = 0; r < 4; r++) h[r] = (f16)acc[cf][r];
            size_t off = ((size_t)(b * DIMC + cc)) * NS + key0;
            *(f16x4*)(vt16 + off) = h;
        }
    }
}

// ---------------- LDS-staged single-product fp16 GEMM: Wq, Wp ----------------
// COMBINE: A-rows come from two K-split attn partials, combined in A-load:
// A = (l0*O0 + l1*O1) / (l0+l1), head index = kk.
template <bool A16, bool OUT16, bool HASBIAS, bool COMBINE>
__global__ __launch_bounds__(256) void gemm_lds_kernel(
    const void* __restrict__ Ain, const f16* __restrict__ Ain2,
    const float* __restrict__ lsum, const f16* __restrict__ W,
    const float* __restrict__ bias, float* __restrict__ outF,
    f16* __restrict__ out16)
{
    __shared__ f16 Bs[64 * WSTRIDE];       // 33 KB -> 4 blocks/CU
    int r0 = blockIdx.x * 64;
    int c0 = blockIdx.y * 64;
    int tid = threadIdx.x;
    for (int i = tid; i < 64 * 32; i += 256) {   // 64 rows x 32 x 16B, coalesced
        int row = i >> 5, seg = i & 31;
        *(f16x8*)(&Bs[row * WSTRIDE + seg * 8]) =
            *(const f16x8*)(W + (size_t)(c0 + row) * DIMC + seg * 8);
    }
    __syncthreads();
    int wave = tid >> 6;
    int lane = tid & 63;
    int s = lane & 15, g = lane >> 4;
    int arow = r0 + wave * 16 + s;

    f32x4 acc[4];
    #pragma unroll
    for (int cf = 0; cf < 4; cf++) {
        float bv = HASBIAS ? bias[c0 + cf * 16 + s] : 0.f;
        acc[cf] = (f32x4){bv, bv, bv, bv};
    }

    #pragma unroll
    for (int kk = 0; kk < 8; kk++) {
        f16x8 a;
        if (COMBINE) {
            f16x8 x0 = *(const f16x8*)((const f16*)Ain + (size_t)arow * DIMC + kk * 32 + 8 * g);
            f16x8 x1 = *(const f16x8*)(Ain2 + (size_t)arow * DIMC + kk * 32 + 8 * g);
            float l0 = lsum[(size_t)arow * NHEADS + kk];
            float l1 = lsum[((size_t)(BATCH * NQ) + arow) * NHEADS + kk];
            float w = 1.f / (l0 + l1);
            float w0 = l0 * w, w1 = l1 * w;
            #pragma unroll
            for (int j = 0; j < 8; j++)
                a[j] = (f16)(w0 * (float)x0[j] + w1 * (float)x1[j]);
        } else if (A16) {
            a = *(const f16x8*)((const f16*)Ain + (size_t)arow * DIMC + kk * 32 + 8 * g);
        } else {
            const float* ap = (const float*)Ain + (size_t)arow * DIMC + kk * 32 + 8 * g;
            float4 a0 = *(const float4*)ap;
            float4 a1 = *(const float4*)(ap + 4);
            a = (f16x8){(f16)a0.x, (f16)a0.y, (f16)a0.z, (f16)a0.w,
                        (f16)a1.x, (f16)a1.y, (f16)a1.z, (f16)a1.w};
        }
        #pragma unroll
        for (int cf = 0; cf < 4; cf++) {
            f16x8 bfrag = *(const f16x8*)(&Bs[(cf * 16 + s) * WSTRIDE + kk * 32 + 8 * g]);
            acc[cf] = MFMA16F(a, bfrag, acc[cf]);
        }
    }

    int rbase = r0 + wave * 16 + 4 * g;
    #pragma unroll
    for (int cf = 0; cf < 4; cf++) {
        int c = c0 + cf * 16 + s;
        #pragma unroll
        for (int r = 0; r < 4; r++) {
            if (OUT16) out16[(size_t)(rbase + r) * DIMC + c] = (f16)acc[cf][r];
            else       outF [(size_t)(rbase + r) * DIMC + c] = acc[cf][r];
        }
    }
}

// ---------------- MFMA flash attention, K-split (8 waves, 256 q/block) ----------------
// 1024 blocks: [split][bh][qt]. Each block: 512 keys. Maxless exp2 softmax;
// writes normalized O per split (f16) + per-(row,head) l into lsum.
__global__ __launch_bounds__(512) void attn_mfma_kernel(
    const f16* __restrict__ qbuf, const f16* __restrict__ kbuf,
    const f16* __restrict__ vt16, const float* __restrict__ conf2,
    f16* __restrict__ opart, float* __restrict__ lsum)
{
    __shared__ f16 Ks[2][TILEK * KSTRIDE];   // 2 x 10240 B
    __shared__ f16 Vs[2][HDIM * VSTRIDE];    // 2 x 8704 B

    int blk  = blockIdx.x;            // NSPLIT*B*H*(NQ/256) = 1024
    int split = blk >> 9;
    int rem  = blk & 511;
    int qt   = rem & 15;              // NQ/256 = 16
    int bh   = rem >> 4;
    int hh   = bh & (NHEADS - 1);
    int b    = bh >> 3;
    int wave = threadIdx.x >> 6;      // 0..7
    int lane = threadIdx.x & 63;
    int s = lane & 15, g = lane >> 4;
    int q0 = qt * 256 + wave * 32;
    int tid = threadIdx.x;

    int kr = tid >> 2, khc = tid & 3;       // 128 rows x 4 x 16B chunks
    int vr = tid >> 4, vjc = tid & 15;      // 32 rows x 16 x 16B chunks
    const f16* kgb = kbuf + ((size_t)(b * NS)) * DIMC + hh * HDIM;
    const f16* vgb = vt16 + ((size_t)(bh * HDIM)) * NS;

    f16x8 qh[2];
    #pragma unroll
    for (int qf = 0; qf < 2; qf++)
        qh[qf] = *(const f16x8*)(qbuf +
            ((size_t)(b * NQ + q0 + qf * 16 + s)) * DIMC + hh * HDIM + 8 * g);

    f32x4 oacc[2][2];
    #pragma unroll
    for (int qf = 0; qf < 2; qf++)
        #pragma unroll
        for (int m = 0; m < 2; m++)
            oacc[qf][m] = (f32x4){0.f, 0.f, 0.f, 0.f};
    float lpart[2] = {0.f, 0.f};      // per-lane partial sum of P

    const float* cfb = conf2 + b * NS + 4 * g;

    int tstart = split * (NS / TILEK / NSPLIT);      // 4 tiles per split
    int tend   = tstart + NS / TILEK / NSPLIT;
    int kbase  = tstart * TILEK;

    // prologue: stage first tile of this split
    f16x8 kA, vA;
    kA = *(const f16x8*)(kgb + (size_t)(kbase + kr) * DIMC + khc * 8);
    vA = *(const f16x8*)(vgb + (size_t)vr * NS + kbase + vjc * 8);
    *(f16x8*)(&Ks[0][kr * KSTRIDE + khc * 8]) = kA;
    *(f16x8*)(&Vs[0][vr * VSTRIDE + vjc * 8]) = vA;
    __syncthreads();

    for (int t = tstart; t < tend; t++) {
        int cur = (t - tstart) & 1;
        if (t < tend - 1) {                  // issue next-tile loads early (T14)
            int kt = (t + 1) * TILEK;
            kA = *(const f16x8*)(kgb + (size_t)(kt + kr) * DIMC + khc * 8);
            vA = *(const f16x8*)(vgb + (size_t)vr * NS + kt + vjc * 8);
        }
        #pragma unroll
        for (int kc = 0; kc < TILEK / 32; kc++) {
            int krow = kc * 32;
            int k0g  = t * TILEK + krow;
            f16x8 khf[2];
            #pragma unroll
            for (int f = 0; f < 2; f++)
                khf[f] = *(const f16x8*)(&Ks[cur][(krow + 16 * f + s) * KSTRIDE + 8 * g]);
            f16x4 vtf[2][2];
            #pragma unroll
            for (int f = 0; f < 2; f++)
                #pragma unroll
                for (int m = 0; m < 2; m++)
                    vtf[f][m] = *(const f16x4*)(&Vs[cur][(16 * m + s) * VSTRIDE
                                                         + krow + 16 * f + 4 * g]);
            float4 cq[2];
            #pragma unroll
            for (int f = 0; f < 2; f++)
                cq[f] = *(const float4*)(cfb + k0g + 16 * f);

            #pragma unroll
            for (int qf = 0; qf < 2; qf++) {
                f32x4 sa[2];
                #pragma unroll
                for (int f = 0; f < 2; f++) {
                    f32x4 z = (f32x4){0.f, 0.f, 0.f, 0.f};
                    sa[f] = MFMA16F(khf[f], qh[qf], z);
                }
                float p[2][4];
                #pragma unroll
                for (int f = 0; f < 2; f++) {
                    const float* cp = &cq[f].x;
                    #pragma unroll
                    for (int r = 0; r < 4; r++) {
                        p[f][r] = EXP2(sa[f][r] * SCALE2F + cp[r]);
                        lpart[qf] += p[f][r];
                    }
                }
                #pragma unroll
                for (int f = 0; f < 2; f++) {
                    union { unsigned u[2]; f16x4 v; } Bp;
                    Bp.u[0] = __builtin_bit_cast(unsigned,
                        __builtin_amdgcn_cvt_pkrtz(p[f][0], p[f][1]));
                    Bp.u[1] = __builtin_bit_cast(unsigned,
                        __builtin_amdgcn_cvt_pkrtz(p[f][2], p[f][3]));
                    #pragma unroll
                    for (int m = 0; m < 2; m++)
                        oacc[qf][m] = MFMA16K16(vtf[f][m], Bp.v, oacc[qf][m]);
                }
            } // qf
        } // kc
        if (t < tend - 1) {
            // no pre-write barrier needed: barrier of tile t-1 already separates
            // the last reads of buffer nxt from these writes
            int nxt = cur ^ 1;
            *(f16x8*)(&Ks[nxt][kr * KSTRIDE + khc * 8]) = kA;
            *(f16x8*)(&Vs[nxt][vr * VSTRIDE + vjc * 8]) = vA;
            __syncthreads();
        }
    } // tile

    // final l-reduction + epilogue: normalized O per split + l
    f16* obase = opart + (size_t)split * ((size_t)BATCH * NQ * DIMC);
    #pragma unroll
    for (int qf = 0; qf < 2; qf++) {
        float l = lpart[qf];
        l += __shfl_xor(l, 16);
        l += __shfl_xor(l, 32);
        float invl = 1.f / l;
        int q = q0 + qf * 16 + s;
        f16* orow = obase + ((size_t)(b * NQ + q)) * DIMC + hh * HDIM;
        #pragma unroll
        for (int m = 0; m < 2; m++) {
            f16x4 o;
            #pragma unroll
            for (int r = 0; r < 4; r++) o[r] = (f16)(oacc[qf][m][r] * invl);
            *(f16x4*)(orow + 16 * m + 4 * g) = o;
        }
        if (g == 0)
            lsum[((size_t)split * (BATCH * NQ) + b * NQ + q) * NHEADS + hh] = l;
    }
}

extern "C" void kernel_launch(void* const* d_in, const int* in_sizes, int n_in,
                              void* d_out, int out_size, void* d_ws, size_t ws_size,
                              hipStream_t stream)
{
    (void)in_sizes; (void)n_in; (void)out_size; (void)ws_size;
    const float* x    = (const float*)d_in[0];
    const float* xsrc = (const float*)d_in[1];
    const float* loc  = (const float*)d_in[2];
    const float* csrc = (const float*)d_in[3];
    const float* Wq   = (const float*)d_in[4];
    const float* Wk   = (const float*)d_in[5];
    const float* Wv   = (const float*)d_in[6];
    const float* Wsr  = (const float*)d_in[7];
    const float* bsr  = (const float*)d_in[8];
    const float* lng  = (const float*)d_in[9];
    const float* lnb  = (const float*)d_in[10];
    const float* Wp   = (const float*)d_in[11];
    const float* bp   = (const float*)d_in[12];
    // d_in[13]=H(64), d_in[14]=W(64): fixed by setup_inputs; h=w=32 hardcoded.

    const int MS = BATCH * NS * DIMC;     // 1,048,576
    const int MQ = BATCH * NQ * DIMC;     // 4,194,304
    const int WSZ = DIMC * DIMC;          // 65,536

    float* ws      = (float*)d_ws;
    float* feat    = ws;                  // MS f32
    float* cnt     = feat + MS;           // 4096
    float* confsum = cnt + BATCH * NS;    // 4096
    float* xs      = confsum + BATCH * NS;// MS f32
    float* conf2   = xs + MS;             // 4096
    float2* stats  = (float2*)(conf2 + BATCH * NS);   // 4096 float2
    int* cursor    = (int*)(stats + BATCH * NS);      // 4096 int
    int* bucket    = cursor + BATCH * NS;             // 4096*64 int = 1 MB
    f16* q16    = (f16*)(bucket + BATCH * NS * BUCKCAP);  // MQ f16
    f16* k16    = q16 + MQ;               // MS f16
    f16* vt16   = k16 + MS;               // MS f16
    f16* opart  = vt16 + MS;              // NSPLIT x MQ f16
    float* lsum = (float*)(opart + (size_t)NSPLIT * MQ);  // NSPLIT*B*NQ*8 = 1 MB
    unsigned short* wsrh = (unsigned short*)(lsum + (size_t)NSPLIT * BATCH * NQ * NHEADS);
    unsigned short* wsrl = wsrh + WSZ;
    f16* wq16 = (f16*)(wsrl + WSZ);       // WSZ f16
    f16* wkv  = wq16 + WSZ;               // 2 x WSZ f16 (Wk rows 0-255, Wv 256-511)
    f16* wp16 = wkv + 2 * WSZ;            // WSZ f16  (total ~48 MB)
    float* outp = (float*)d_out;

    prep_kernel<<<dim3(64, 6), 256, 0, stream>>>(
        Wsr, Wq, Wk, Wv, Wp, wsrh, wsrl, wq16, wkv, wp16, cursor);
    build_kernel<<<BATCH * NQ / 256, 256, 0, stream>>>(loc, cursor, bucket);
    gather_kernel<<<BATCH * NS / GCELLS, 256, 0, stream>>>(
        xsrc, csrc, cursor, bucket, feat, cnt, confsum);
    gemm_sr_kernel<<<BATCH * NS / 16, 256, 0, stream>>>(
        feat, cnt, confsum, wsrh, wsrl, bsr, xs, stats, conf2);
    gemm_lds_kernel<false, true, false, false><<<dim3(BATCH * NQ / 64, 4), 256, 0, stream>>>(
        x, nullptr, nullptr, wq16, nullptr, nullptr, q16);
    gemm_kv_kernel<<<dim3(BATCH * NS / 16, 4), 256, 0, stream>>>(
        xs, stats, lng, lnb, wkv, k16, vt16);
    attn_mfma_kernel<<<NSPLIT * BATCH * NHEADS * (NQ / 256), 512, 0, stream>>>(
        q16, k16, vt16, conf2, opart, lsum);
    gemm_lds_kernel<true, false, true, true><<<dim3(BATCH * NQ / 64, 4), 256, 0, stream>>>(
        opart, opart + (size_t)MQ, lsum, wp16, bp, outp, nullptr);
}

// Round 22
// 106.624 us; speedup vs baseline: 1.0512x; 1.0512x over previous
//
#include <hip/hip_runtime.h>
#include <math.h>

#define DIMC   256
#define NQ     4096
#define BATCH  4
#define NS     1024    // (H/SR)*(W/SR) = 32*32
#define WG     32
#define HG     32
#define NHEADS 8
#define HDIM   32
#define TILEK  128     // keys staged per LDS tile
#define KSTRIDE 40     // f16 per K row in LDS
#define VSTRIDE 136    // f16 per Vt row in LDS
#define WSTRIDE 264    // f16 per B row in LDS-staged GEMM (528B, 16B-aligned)
#define BUCKCAP 64     // tokens-per-cell bucket capacity (= wave size)
#define GCELLS 4       // cells per gather block
#define SCALE_ATTN 0.17677669529663687
#define LOG2E 1.4426950408889634
#define SCALE2F ((float)(SCALE_ATTN * LOG2E))

extern "C" __device__ float __ocml_native_exp2_f32(float);
#if __has_builtin(__builtin_amdgcn_exp2f)
#define EXP2(x) __builtin_amdgcn_exp2f(x)
#else
#define EXP2(x) __ocml_native_exp2_f32(x)
#endif

typedef _Float16 f16;
typedef __attribute__((ext_vector_type(8))) __bf16    bf16x8;
typedef __attribute__((ext_vector_type(8))) _Float16  f16x8;
typedef __attribute__((ext_vector_type(4))) _Float16  f16x4;
typedef __attribute__((ext_vector_type(4))) float     f32x4;

#define MFMA16B(A, B, C)  __builtin_amdgcn_mfma_f32_16x16x32_bf16((A), (B), (C), 0, 0, 0)
#define MFMA16F(A, B, C)  __builtin_amdgcn_mfma_f32_16x16x32_f16((A), (B), (C), 0, 0, 0)
#define MFMA16K16(A, B, C) __builtin_amdgcn_mfma_f32_16x16x16f16((A), (B), (C), 0, 0, 0)

static __device__ __forceinline__ unsigned short bf16_hi(float v) {
    return __builtin_bit_cast(unsigned short, (__bf16)v);
}

// ---------------- prep: wprep (y=0..4) + zero cursor (y=5) ----------------
__global__ __launch_bounds__(256) void prep_kernel(
    const float* __restrict__ Wsr, const float* __restrict__ Wq,
    const float* __restrict__ Wk, const float* __restrict__ Wv,
    const float* __restrict__ Wp,
    unsigned short* __restrict__ wsrh, unsigned short* __restrict__ wsrl,
    f16* __restrict__ wq16, f16* __restrict__ wkv, f16* __restrict__ wp16,
    int* __restrict__ cursor)
{
    int m = blockIdx.y;
    if (m == 5) {
        int i = blockIdx.x * 256 + threadIdx.x;
        if (i < BATCH * NS) cursor[i] = 0;
        return;
    }
    int i = (blockIdx.x * 256 + threadIdx.x) * 4;   // grid.x = 64 -> 65536 elems
    if (m == 0) {
        float4 v = *(const float4*)(Wsr + i);
        float vv[4] = {v.x, v.y, v.z, v.w};
        ushort4 h, l;
        unsigned short* hp = &h.x; unsigned short* lp = &l.x;
        #pragma unroll
        for (int j = 0; j < 4; j++) {
            __bf16 hb = (__bf16)vv[j];
            hp[j] = __builtin_bit_cast(unsigned short, hb);
            lp[j] = bf16_hi(vv[j] - (float)hb);
        }
        *(ushort4*)(wsrh + i) = h;
        *(ushort4*)(wsrl + i) = l;
    } else {
        const float* W = (m == 1) ? Wq : (m == 2) ? Wk : (m == 3) ? Wv : Wp;
        f16* O = (m == 1) ? wq16 : (m == 2) ? wkv
               : (m == 3) ? (wkv + DIMC * DIMC) : wp16;
        float4 v = *(const float4*)(W + i);
        f16x4 h = {(f16)v.x, (f16)v.y, (f16)v.z, (f16)v.w};
        *(f16x4*)(O + i) = h;
    }
}

// ---------------- build: token -> cell buckets (16K int atomics only) ----------------
__global__ __launch_bounds__(256) void build_kernel(
    const float* __restrict__ loc, int* __restrict__ cursor,
    int* __restrict__ bucket)
{
    int token = blockIdx.x * 256 + threadIdx.x;   // B*NQ
    int b = token >> 12;
    float lx = loc[token * 2 + 0];
    float ly = loc[token * 2 + 1];
    lx = fminf(fmaxf(lx, 0.f), 1.f) * (float)(WG - 1);
    ly = fminf(fmaxf(ly, 0.f), 1.f) * (float)(HG - 1);
    int ix = (int)rintf(lx);         // round-half-even, matches jnp.round
    int iy = (int)rintf(ly);
    int cell = b * NS + iy * WG + ix;
    int slot = atomicAdd(&cursor[cell], 1);
    if (slot < BUCKCAP) bucket[cell * BUCKCAP + slot] = token;
}

// ---------------- gather standalone (1024 blocks, 4 cells each) ----------------
__global__ __launch_bounds__(256) void gather_kernel(
    const float* __restrict__ xsrc, const float* __restrict__ csrc,
    const int* __restrict__ cursor, const int* __restrict__ bucket,
    float* __restrict__ feat, float* __restrict__ cnt, float* __restrict__ confsum)
{
    __shared__ int bks[GCELLS][BUCKCAP];
    __shared__ int ns[GCELLS];
    int cell0 = blockIdx.x * GCELLS;
    int tid = threadIdx.x;
    int jw = tid >> 6, slot = tid & 63;      // wave jw <-> cell jw
    int cj = cell0 + jw;
    int rawn = cursor[cj];
    if (slot == 0) ns[jw] = min(rawn, BUCKCAP);
    bks[jw][slot] = bucket[(size_t)cj * BUCKCAP + slot];
    __syncthreads();
    int nw = ns[jw];
    float cv = (slot < nw) ? csrc[bks[jw][slot]] : 0.f;
    #pragma unroll
    for (int off = 1; off < 64; off <<= 1) cv += __shfl_xor(cv, off);
    if (slot == 0) { confsum[cj] = cv; cnt[cj] = (float)rawn; }
    int c = tid;
    for (int j = 0; j < GCELLS; j++) {
        int n = ns[j];
        float s0 = 0.f, s1 = 0.f, s2 = 0.f, s3 = 0.f;
        int i = 0;
        for (; i + 4 <= n; i += 4) {
            s0 += xsrc[(size_t)bks[j][i]     * DIMC + c];
            s1 += xsrc[(size_t)bks[j][i + 1] * DIMC + c];
            s2 += xsrc[(size_t)bks[j][i + 2] * DIMC + c];
            s3 += xsrc[(size_t)bks[j][i + 3] * DIMC + c];
        }
        for (; i < n; i++)
            s0 += xsrc[(size_t)bks[j][i] * DIMC + c];
        feat[(size_t)(cell0 + j) * DIMC + c] = (s0 + s1) + (s2 + s3);
    }
}

// ---------------- bf16x2-split GEMM + fused featfin + LN stats + conf2: Wsr ----------------
__global__ __launch_bounds__(256) void gemm_sr_kernel(
    const float* __restrict__ A, const float* __restrict__ cnt,
    const float* __restrict__ confsum,
    const unsigned short* __restrict__ Whi, const unsigned short* __restrict__ Wlo,
    const float* __restrict__ bias, float* __restrict__ outF,
    float2* __restrict__ stats, float* __restrict__ conf2)
{
    int r0 = blockIdx.x * 16;               // 256 blocks
    int wave = threadIdx.x >> 6;
    int lane = threadIdx.x & 63;
    int s = lane & 15, g = lane >> 4;
    int arow = r0 + s;
    int cb = wave * 64;                     // wave's 64-col slice
    const float* ap = A + (size_t)arow * DIMC + 8 * g;
    float cv = cnt[arow];
    float invr = (cv > 0.f) ? 1.f / (cv + 1e-6f) : 0.f;

    f32x4 acc[4];
    #pragma unroll
    for (int cf = 0; cf < 4; cf++) {
        float bv = bias[cb + cf * 16 + s];
        acc[cf] = (f32x4){bv, bv, bv, bv};
    }

    #pragma unroll
    for (int kk = 0; kk < 8; kk++) {
        float4 a0 = *(const float4*)(ap + kk * 32);
        float4 a1 = *(const float4*)(ap + kk * 32 + 4);
        float av[8] = {a0.x, a0.y, a0.z, a0.w, a1.x, a1.y, a1.z, a1.w};
        bf16x8 ah, al;
        #pragma unroll
        for (int j = 0; j < 8; j++) {
            float v = av[j] * invr;              // fused featfin
            __bf16 hb = (__bf16)v;
            ah[j] = hb;
            al[j] = (__bf16)(v - (float)hb);
        }
        #pragma unroll
        for (int cf = 0; cf < 4; cf++) {
            size_t woff = (size_t)(cb + cf * 16 + s) * DIMC + kk * 32 + 8 * g;
            bf16x8 bh = *(const bf16x8*)(Whi + woff);
            bf16x8 bl = *(const bf16x8*)(Wlo + woff);
            acc[cf] = MFMA16B(ah, bh, acc[cf]);
            acc[cf] = MFMA16B(al, bh, acc[cf]);
            acc[cf] = MFMA16B(ah, bl, acc[cf]);
        }
    }

    int rbase = r0 + 4 * g;
    #pragma unroll
    for (int cf = 0; cf < 4; cf++) {
        int c = cb + cf * 16 + s;
        #pragma unroll
        for (int r = 0; r < 4; r++)
            outF[(size_t)(rbase + r) * DIMC + c] = acc[cf][r];
    }
    // fused LN stats
    float psum[4], psq[4];
    #pragma unroll
    for (int r = 0; r < 4; r++) {
        psum[r] = 0.f; psq[r] = 0.f;
        #pragma unroll
        for (int cf = 0; cf < 4; cf++) {
            float v = acc[cf][r];
            psum[r] += v; psq[r] += v * v;
        }
    }
    #pragma unroll
    for (int off = 1; off < 16; off <<= 1)
        #pragma unroll
        for (int r = 0; r < 4; r++) {
            psum[r] += __shfl_xor(psum[r], off);
            psq[r]  += __shfl_xor(psq[r], off);
        }
    __shared__ float ssum[4][16], ssq[4][16];
    if (s == 0)
        #pragma unroll
        for (int r = 0; r < 4; r++) {
            ssum[wave][4 * g + r] = psum[r];
            ssq[wave][4 * g + r]  = psq[r];
        }
    __syncthreads();
    if (threadIdx.x < 16) {
        int rr = threadIdx.x;
        float su = ssum[0][rr] + ssum[1][rr] + ssum[2][rr] + ssum[3][rr];
        float sq = ssq[0][rr] + ssq[1][rr] + ssq[2][rr] + ssq[3][rr];
        float mu  = su * (1.f / DIMC);
        float var = sq * (1.f / DIMC) - mu * mu;
        stats[r0 + rr] = make_float2(mu, rsqrtf(var + 1e-5f));
        float cv2 = cnt[r0 + rr];
        float iv2 = (cv2 > 0.f) ? 1.f / (cv2 + 1e-6f) : 0.f;
        conf2[r0 + rr] = confsum[r0 + rr] * iv2 * (float)LOG2E;
    }
}

// ---------------- fused LN + K/V GEMM (single f16 product) ----------------
__global__ __launch_bounds__(256) void gemm_kv_kernel(
    const float* __restrict__ xs, const float2* __restrict__ stats,
    const float* __restrict__ lng, const float* __restrict__ lnb,
    const f16* __restrict__ wkv, f16* __restrict__ k16, f16* __restrict__ vt16)
{
    int r0 = blockIdx.x * 16;
    int cb0 = blockIdx.y * 128;            // 0..384 over N=512
    int wave = threadIdx.x >> 6;
    int lane = threadIdx.x & 63;
    int s = lane & 15, g = lane >> 4;
    int arow = r0 + s;
    int cb = cb0 + wave * 32;
    float2 st = stats[arow];               // mu, rs
    const float* ap = xs + (size_t)arow * DIMC + 8 * g;

    f32x4 acc[2];
    acc[0] = (f32x4){0.f, 0.f, 0.f, 0.f};
    acc[1] = (f32x4){0.f, 0.f, 0.f, 0.f};

    #pragma unroll
    for (int kk = 0; kk < 8; kk++) {
        float4 a0 = *(const float4*)(ap + kk * 32);
        float4 a1 = *(const float4*)(ap + kk * 32 + 4);
        float4 g0 = *(const float4*)(lng + kk * 32 + 8 * g);
        float4 g1 = *(const float4*)(lng + kk * 32 + 8 * g + 4);
        float4 b0 = *(const float4*)(lnb + kk * 32 + 8 * g);
        float4 b1 = *(const float4*)(lnb + kk * 32 + 8 * g + 4);
        float av[8] = {a0.x, a0.y, a0.z, a0.w, a1.x, a1.y, a1.z, a1.w};
        float gv[8] = {g0.x, g0.y, g0.z, g0.w, g1.x, g1.y, g1.z, g1.w};
        float bv[8] = {b0.x, b0.y, b0.z, b0.w, b1.x, b1.y, b1.z, b1.w};
        f16x8 a;
        #pragma unroll
        for (int j = 0; j < 8; j++)
            a[j] = (f16)(((av[j] - st.x) * st.y) * gv[j] + bv[j]);
        #pragma unroll
        for (int cf = 0; cf < 2; cf++) {
            f16x8 bfrag = *(const f16x8*)(wkv + (size_t)(cb + cf * 16 + s) * DIMC
                                              + kk * 32 + 8 * g);
            acc[cf] = MFMA16F(a, bfrag, acc[cf]);
        }
    }

    int rbase = r0 + 4 * g;
    if (cb0 < 256) {                       // K channels: row-major
        #pragma unroll
        for (int cf = 0; cf < 2; cf++) {
            int c = cb + cf * 16 + s;
            #pragma unroll
            for (int r = 0; r < 4; r++)
                k16[(size_t)(rbase + r) * DIMC + c] = (f16)acc[cf][r];
        }
    } else {                               // V channels: transposed vt16
        int b = rbase >> 10;
        int key0 = rbase & 1023;
        #pragma unroll
        for (int cf = 0; cf < 2; cf++) {
            int cc = cb + cf * 16 + s - 256;
            f16x4 h;
            #pragma unroll
            for (int r = 0; r < 4; r++) h[r] = (f16)acc[cf][r];
            size_t off = ((size_t)(b * DIMC + cc)) * NS + key0;
            *(f16x4*)(vt16 + off) = h;
        }
    }
}

// ---------------- LDS-staged single-product fp16 GEMM: Wq, Wp ----------------
// Block = 64 rows x 64 cols; 4 waves (16-row strips) share one B-slice staged
// in LDS (64x256 f16, coalesced) -> B global requests drop ~16x.
template <bool A16, bool OUT16, bool HASBIAS>
__global__ __launch_bounds__(256) void gemm_lds_kernel(
    const void* __restrict__ Ain, const f16* __restrict__ W,
    const float* __restrict__ bias, float* __restrict__ outF,
    f16* __restrict__ out16)
{
    __shared__ f16 Bs[64 * WSTRIDE];       // 33 KB -> 4 blocks/CU
    int r0 = blockIdx.x * 64;
    int c0 = blockIdx.y * 64;
    int tid = threadIdx.x;
    for (int i = tid; i < 64 * 32; i += 256) {   // 64 rows x 32 x 16B, coalesced
        int row = i >> 5, seg = i & 31;
        *(f16x8*)(&Bs[row * WSTRIDE + seg * 8]) =
            *(const f16x8*)(W + (size_t)(c0 + row) * DIMC + seg * 8);
    }
    __syncthreads();
    int wave = tid >> 6;
    int lane = tid & 63;
    int s = lane & 15, g = lane >> 4;
    int arow = r0 + wave * 16 + s;

    f32x4 acc[4];
    #pragma unroll
    for (int cf = 0; cf < 4; cf++) {
        float bv = HASBIAS ? bias[c0 + cf * 16 + s] : 0.f;
        acc[cf] = (f32x4){bv, bv, bv, bv};
    }

    #pragma unroll
    for (int kk = 0; kk < 8; kk++) {
        f16x8 a;
        if (A16) {
            a = *(const f16x8*)((const f16*)Ain + (size_t)arow * DIMC + kk * 32 + 8 * g);
        } else {
            const float* ap = (const float*)Ain + (size_t)arow * DIMC + kk * 32 + 8 * g;
            float4 a0 = *(const float4*)ap;
            float4 a1 = *(const float4*)(ap + 4);
            a = (f16x8){(f16)a0.x, (f16)a0.y, (f16)a0.z, (f16)a0.w,
                        (f16)a1.x, (f16)a1.y, (f16)a1.z, (f16)a1.w};
        }
        #pragma unroll
        for (int cf = 0; cf < 4; cf++) {
            f16x8 bfrag = *(const f16x8*)(&Bs[(cf * 16 + s) * WSTRIDE + kk * 32 + 8 * g]);
            acc[cf] = MFMA16F(a, bfrag, acc[cf]);
        }
    }

    int rbase = r0 + wave * 16 + 4 * g;
    #pragma unroll
    for (int cf = 0; cf < 4; cf++) {
        int c = c0 + cf * 16 + s;
        #pragma unroll
        for (int r = 0; r < 4; r++) {
            if (OUT16) out16[(size_t)(rbase + r) * DIMC + c] = (f16)acc[cf][r];
            else       outF [(size_t)(rbase + r) * DIMC + c] = acc[cf][r];
        }
    }
}

// ---------------- MFMA flash attention (8 waves, 256 q/block, maxless exp2) ----------------
__global__ __launch_bounds__(512) void attn_mfma_kernel(
    const f16* __restrict__ qbuf, const f16* __restrict__ kbuf,
    const f16* __restrict__ vt16, const float* __restrict__ conf2,
    f16* __restrict__ abuf)
{
    __shared__ f16 Ks[2][TILEK * KSTRIDE];   // 2 x 10240 B
    __shared__ f16 Vs[2][HDIM * VSTRIDE];    // 2 x 8704 B

    int blk  = blockIdx.x;            // B*H*(NQ/256) = 512
    int qt   = blk & 15;              // NQ/256 = 16
    int bh   = blk >> 4;
    int hh   = bh & (NHEADS - 1);
    int b    = bh >> 3;
    int wave = threadIdx.x >> 6;      // 0..7
    int lane = threadIdx.x & 63;
    int s = lane & 15, g = lane >> 4;
    int q0 = qt * 256 + wave * 32;
    int tid = threadIdx.x;

    int kr = tid >> 2, khc = tid & 3;       // 128 rows x 4 x 16B chunks
    int vr = tid >> 4, vjc = tid & 15;      // 32 rows x 16 x 16B chunks
    const f16* kgb = kbuf + ((size_t)(b * NS)) * DIMC + hh * HDIM;
    const f16* vgb = vt16 + ((size_t)(bh * HDIM)) * NS;

    f16x8 qh[2];
    #pragma unroll
    for (int qf = 0; qf < 2; qf++)
        qh[qf] = *(const f16x8*)(qbuf +
            ((size_t)(b * NQ + q0 + qf * 16 + s)) * DIMC + hh * HDIM + 8 * g);

    f32x4 oacc[2][2];
    #pragma unroll
    for (int qf = 0; qf < 2; qf++)
        #pragma unroll
        for (int m = 0; m < 2; m++)
            oacc[qf][m] = (f32x4){0.f, 0.f, 0.f, 0.f};
    float lpart[2] = {0.f, 0.f};      // per-lane partial sum of P

    const float* cfb = conf2 + b * NS + 4 * g;

    // prologue: stage tile 0 (one K chunk + one V chunk per thread)
    f16x8 kA, vA;
    kA = *(const f16x8*)(kgb + (size_t)kr * DIMC + khc * 8);
    vA = *(const f16x8*)(vgb + (size_t)vr * NS + vjc * 8);
    *(f16x8*)(&Ks[0][kr * KSTRIDE + khc * 8]) = kA;
    *(f16x8*)(&Vs[0][vr * VSTRIDE + vjc * 8]) = vA;
    __syncthreads();

    for (int t = 0; t < NS / TILEK; t++) {
        int cur = t & 1;
        if (t < NS / TILEK - 1) {            // issue next-tile loads early (T14)
            int kt = (t + 1) * TILEK;
            kA = *(const f16x8*)(kgb + (size_t)(kt + kr) * DIMC + khc * 8);
            vA = *(const f16x8*)(vgb + (size_t)vr * NS + kt + vjc * 8);
        }
        #pragma unroll
        for (int kc = 0; kc < TILEK / 32; kc++) {
            int krow = kc * 32;
            int k0g  = t * TILEK + krow;
            f16x8 khf[2];
            #pragma unroll
            for (int f = 0; f < 2; f++)
                khf[f] = *(const f16x8*)(&Ks[cur][(krow + 16 * f + s) * KSTRIDE + 8 * g]);
            f16x4 vtf[2][2];
            #pragma unroll
            for (int f = 0; f < 2; f++)
                #pragma unroll
                for (int m = 0; m < 2; m++)
                    vtf[f][m] = *(const f16x4*)(&Vs[cur][(16 * m + s) * VSTRIDE
                                                         + krow + 16 * f + 4 * g]);
            float4 cq[2];
            #pragma unroll
            for (int f = 0; f < 2; f++)
                cq[f] = *(const float4*)(cfb + k0g + 16 * f);

            #pragma unroll
            for (int qf = 0; qf < 2; qf++) {
                f32x4 sa[2];
                #pragma unroll
                for (int f = 0; f < 2; f++) {
                    f32x4 z = (f32x4){0.f, 0.f, 0.f, 0.f};
                    sa[f] = MFMA16F(khf[f], qh[qf], z);
                }
                float p[2][4];
                #pragma unroll
                for (int f = 0; f < 2; f++) {
                    const float* cp = &cq[f].x;
                    #pragma unroll
                    for (int r = 0; r < 4; r++) {
                        p[f][r] = EXP2(sa[f][r] * SCALE2F + cp[r]);
                        lpart[qf] += p[f][r];
                    }
                }
                #pragma unroll
                for (int f = 0; f < 2; f++) {
                    union { unsigned u[2]; f16x4 v; } Bp;
                    Bp.u[0] = __builtin_bit_cast(unsigned,
                        __builtin_amdgcn_cvt_pkrtz(p[f][0], p[f][1]));
                    Bp.u[1] = __builtin_bit_cast(unsigned,
                        __builtin_amdgcn_cvt_pkrtz(p[f][2], p[f][3]));
                    #pragma unroll
                    for (int m = 0; m < 2; m++)
                        oacc[qf][m] = MFMA16K16(vtf[f][m], Bp.v, oacc[qf][m]);
                }
            } // qf
        } // kc
        if (t < NS / TILEK - 1) {
            // no pre-write barrier needed: barrier of tile t-1 already separates
            // the last reads of buffer nxt from these writes
            int nxt = cur ^ 1;
            *(f16x8*)(&Ks[nxt][kr * KSTRIDE + khc * 8]) = kA;
            *(f16x8*)(&Vs[nxt][vr * VSTRIDE + vjc * 8]) = vA;
            __syncthreads();
        }
    } // tile

    // final l-reduction (once) + epilogue
    #pragma unroll
    for (int qf = 0; qf < 2; qf++) {
        float l = lpart[qf];
        l += __shfl_xor(l, 16);
        l += __shfl_xor(l, 32);
        float invl = 1.f / l;
        f16* orow = abuf + ((size_t)(b * NQ + q0 + qf * 16 + s)) * DIMC + hh * HDIM;
        #pragma unroll
        for (int m = 0; m < 2; m++) {
            f16x4 o;
            #pragma unroll
            for (int r = 0; r < 4; r++) o[r] = (f16)(oacc[qf][m][r] * invl);
            *(f16x4*)(orow + 16 * m + 4 * g) = o;
        }
    }
}

extern "C" void kernel_launch(void* const* d_in, const int* in_sizes, int n_in,
                              void* d_out, int out_size, void* d_ws, size_t ws_size,
                              hipStream_t stream)
{
    (void)in_sizes; (void)n_in; (void)out_size; (void)ws_size;
    const float* x    = (const float*)d_in[0];
    const float* xsrc = (const float*)d_in[1];
    const float* loc  = (const float*)d_in[2];
    const float* csrc = (const float*)d_in[3];
    const float* Wq   = (const float*)d_in[4];
    const float* Wk   = (const float*)d_in[5];
    const float* Wv   = (const float*)d_in[6];
    const float* Wsr  = (const float*)d_in[7];
    const float* bsr  = (const float*)d_in[8];
    const float* lng  = (const float*)d_in[9];
    const float* lnb  = (const float*)d_in[10];
    const float* Wp   = (const float*)d_in[11];
    const float* bp   = (const float*)d_in[12];
    // d_in[13]=H(64), d_in[14]=W(64): fixed by setup_inputs; h=w=32 hardcoded.

    const int MS = BATCH * NS * DIMC;     // 1,048,576
    const int MQ = BATCH * NQ * DIMC;     // 4,194,304
    const int WSZ = DIMC * DIMC;          // 65,536

    float* ws      = (float*)d_ws;
    float* feat    = ws;                  // MS f32
    float* cnt     = feat + MS;           // 4096
    float* confsum = cnt + BATCH * NS;    // 4096
    float* xs      = confsum + BATCH * NS;// MS f32
    float* conf2   = xs + MS;             // 4096
    float2* stats  = (float2*)(conf2 + BATCH * NS);   // 4096 float2
    int* cursor    = (int*)(stats + BATCH * NS);      // 4096 int
    int* bucket    = cursor + BATCH * NS;             // 4096*64 int = 1 MB
    f16* q16    = (f16*)(bucket + BATCH * NS * BUCKCAP);  // MQ f16
    f16* k16    = q16 + MQ;               // MS f16
    f16* vt16   = k16 + MS;               // MS f16
    f16* abuf16 = vt16 + MS;              // MQ f16
    unsigned short* wsrh = (unsigned short*)(abuf16 + MQ);  // 2 x WSZ bf16
    unsigned short* wsrl = wsrh + WSZ;
    f16* wq16 = (f16*)(wsrl + WSZ);       // WSZ f16
    f16* wkv  = wq16 + WSZ;               // 2 x WSZ f16 (Wk rows 0-255, Wv 256-511)
    f16* wp16 = wkv + 2 * WSZ;            // WSZ f16
    float* outp = (float*)d_out;

    prep_kernel<<<dim3(64, 6), 256, 0, stream>>>(
        Wsr, Wq, Wk, Wv, Wp, wsrh, wsrl, wq16, wkv, wp16, cursor);
    build_kernel<<<BATCH * NQ / 256, 256, 0, stream>>>(loc, cursor, bucket);
    gather_kernel<<<BATCH * NS / GCELLS, 256, 0, stream>>>(
        xsrc, csrc, cursor, bucket, feat, cnt, confsum);
    gemm_sr_kernel<<<BATCH * NS / 16, 256, 0, stream>>>(
        feat, cnt, confsum, wsrh, wsrl, bsr, xs, stats, conf2);
    gemm_lds_kernel<false, true, false><<<dim3(BATCH * NQ / 64, 4), 256, 0, stream>>>(
        x, wq16, nullptr, nullptr, q16);
    gemm_kv_kernel<<<dim3(BATCH * NS / 16, 4), 256, 0, stream>>>(
        xs, stats, lng, lnb, wkv, k16, vt16);
    attn_mfma_kernel<<<BATCH * NHEADS * (NQ / 256), 512, 0, stream>>>(
        q16, k16, vt16, conf2, abuf16);
    gemm_lds_kernel<true, false, true><<<dim3(BATCH * NQ / 64, 4), 256, 0, stream>>>(
        abuf16, wp16, bp, outp, nullptr);
}